// Round 5
// baseline (235.232 us; speedup 1.0000x reference)
//
#include <hip/hip_runtime.h>
#include <stdint.h>

// Problem constants (from reference)
#define BB 16
#define HH 299
#define WW 299
#define KK 8
#define HWPIX (HH * WW)        // 89401
#define NPIX (BB * HWPIX)      // 1430416
#define TPB 256
#define GRID 768               // 3 blocks/CU resident on 256 CUs, uniform work
#define GSPAN (GRID * TPB)     // 196608
#define ITERS ((NPIX + GSPAN - 1) / GSPAN)  // 8

typedef float f4 __attribute__((ext_vector_type(4)));

struct Streams { f4 w0, w1, i0, i1, o; };

static __device__ __forceinline__ Streams load_streams(
    const f4* __restrict__ wi4, const f4* __restrict__ ori, int p, bool act) {
    int pc = act ? p : 0;
    int b   = pc / HWPIX;
    int rem = pc - b * HWPIX;
    size_t wb = ((size_t)(2 * b) * HWPIX + rem) * 2;  // f4 units
    size_t ib = wb + (size_t)HWPIX * 2;
    Streams s;
    s.w0 = __builtin_nontemporal_load(wi4 + wb);
    s.w1 = __builtin_nontemporal_load(wi4 + wb + 1);
    s.i0 = __builtin_nontemporal_load(wi4 + ib);
    s.i1 = __builtin_nontemporal_load(wi4 + ib + 1);
    s.o  = __builtin_nontemporal_load(ori + pc);
    return s;
}

__global__ __launch_bounds__(TPB, 3) void gauss_net_kernel(
    const f4* __restrict__ spatial,  // (N_POINTS, 4)
    const f4* __restrict__ wi4,      // (B, 2, H, W, K) as f4
    const f4* __restrict__ ori,      // (B, H, W, 4)
    float* __restrict__ out)
{
    const int tid = blockIdx.x * TPB + threadIdx.x;

    // Output layout (flat float offsets)
    f4*    out_x    = (f4*)out;
    f4*    out_rgba = out_x + NPIX;
    float* out_cla  = (float*)(out_rgba + NPIX);
    f4*    out_ori  = (f4*)(out_cla + (size_t)BB * 3 * HWPIX);
    float* out_ocla = (float*)(out_ori + NPIX);

    // Pipeline prologue: streams for iteration 0
    Streams cur = load_streams(wi4, ori, tid, tid < NPIX);

#pragma unroll 1
    for (int it = 0; it < ITERS; ++it) {
        const int  p   = it * GSPAN + tid;
        const bool act = (p < NPIX);

        // 1) Issue gathers for current iteration (indices already resident
        //    from the previous iteration's prefetch).
        int id[KK] = { (int)cur.i0.x, (int)cur.i0.y, (int)cur.i0.z, (int)cur.i0.w,
                       (int)cur.i1.x, (int)cur.i1.y, (int)cur.i1.z, (int)cur.i1.w };
        f4 g[KK];
#pragma unroll
        for (int k = 0; k < KK; ++k) g[k] = spatial[id[k]];

        // 2) Prefetch next iteration's streams AFTER the gathers, so waiting
        //    on the gathers (in-order vmcnt) leaves the prefetch in flight.
        const int pn = p + GSPAN;
        Streams nxt = load_streams(wi4, ori, pn, pn < NPIX);

        // 3) Consume gathers, epilogue, stores.
        float wt[KK] = { cur.w0.x, cur.w0.y, cur.w0.z, cur.w0.w,
                         cur.w1.x, cur.w1.y, cur.w1.z, cur.w1.w };
        f4 acc = (f4){0.f, 0.f, 0.f, 0.f};
#pragma unroll
        for (int k = 0; k < KK; ++k) acc += g[k] * wt[k];

        if (act) {
            const int b   = p / HWPIX;
            const int rem = p - b * HWPIX;
            f4 ov = cur.o;
            float alpha = acc.w * (1.0f / 255.0f);
            float r  = fmaf(acc.x, alpha, ov.x);
            float gr = fmaf(acc.y, alpha, ov.y);
            float bl = fmaf(acc.z, alpha, ov.z);
            bool oa_pos = (ov.w > 0.0f);
            if (!oa_pos) { r = 0.f; gr = 0.f; bl = 0.f; }

            float cr = fminf(fmaxf(r,  0.f), 255.f);
            float cg = fminf(fmaxf(gr, 0.f), 255.f);
            float cb = fminf(fmaxf(bl, 0.f), 255.f);
            float ca = fminf(fmaxf(ov.w, 0.f), 255.f);

            __builtin_nontemporal_store(acc, out_x + p);
            __builtin_nontemporal_store((f4){cr, cg, cb, ca}, out_rgba + p);
            __builtin_nontemporal_store(ov, out_ori + p);

            size_t cbase = (size_t)b * 3 * HWPIX + rem;
            bool ca_pos = (ca > 0.0f);
            __builtin_nontemporal_store(ca_pos ? cr : 255.0f, out_cla + cbase);
            __builtin_nontemporal_store(ca_pos ? cg : 255.0f, out_cla + cbase + HWPIX);
            __builtin_nontemporal_store(ca_pos ? cb : 255.0f, out_cla + cbase + 2 * HWPIX);

            __builtin_nontemporal_store(oa_pos ? ov.x : 255.0f, out_ocla + cbase);
            __builtin_nontemporal_store(oa_pos ? ov.y : 255.0f, out_ocla + cbase + HWPIX);
            __builtin_nontemporal_store(oa_pos ? ov.z : 255.0f, out_ocla + cbase + 2 * HWPIX);
        }

        cur = nxt;
    }
}

extern "C" void kernel_launch(void* const* d_in, const int* in_sizes, int n_in,
                              void* d_out, int out_size, void* d_ws, size_t ws_size,
                              hipStream_t stream) {
    const f4* spatial = (const f4*)d_in[0];
    const f4* wi4     = (const f4*)d_in[1];
    const f4* ori     = (const f4*)d_in[2];
    float* out = (float*)d_out;

    gauss_net_kernel<<<GRID, TPB, 0, stream>>>(spatial, wi4, ori, out);
}